// Round 7
// baseline (157.519 us; speedup 1.0000x reference)
//
#include <hip/hip_runtime.h>
#include <hip/hip_bf16.h>

// EdgeConv: B=8, C=64, N=4096, K=16, O=64
// Key identity: out[n] = relu(F[n] + max_k G[src[n,k]]),
//   F = x@(Wa-Wb)+bias, G = x@Wb   (max commutes with lane-constant add; relu with max)
// k1: dense GEMM -> FG[B*N][128] bf16 (cols 0-63 = F, 64-127 = G)
// k2: per-node wave: 16 coalesced 128B G-row gathers + fmax + relu, coalesced out.
// NOTE: plain block mapping (no XCD swizzle) — R6's bid&7 swizzle caused stale-G
// post-timing divergence (workgroup->XCD assignment is undefined; don't correlate
// writer/reader placement). Fences added for cross-XCD visibility of FG.

#define BB 8
#define CC 64
#define NN 4096
#define KK 16
#define OO 64

typedef __bf16 bf16x8 __attribute__((ext_vector_type(8)));
typedef float f32x4 __attribute__((ext_vector_type(4)));

union Frag { int4 i; bf16x8 v; };
union PackA { bf16x8 v; __hip_bfloat16 h[8]; };

static __device__ __forceinline__ float bf2f(unsigned short u) {
    union { unsigned int i; float f; } c; c.i = ((unsigned int)u) << 16; return c.f;
}

// ---------------- k1: FG = [x@(Wa-Wb)+bias | x@Wb] ----------------
// Block: 64 nodes of one batch. M=64, N2=128, K=64. 4 waves, 16 MFMA each.
__global__ __launch_bounds__(256, 3) void fg_gemm(
    const float* __restrict__ x, const float* __restrict__ W,
    const float* __restrict__ bias, __hip_bfloat16* __restrict__ FG) {
    __shared__ float xt[64][65];      // [c][node] f32, +1 pad
    __shared__ int4 wfl[16][64];      // B-frags: [ks*8+ot][lane]

    int t = threadIdx.x, w = t >> 6, l = t & 63;
    int b = blockIdx.x >> 6;          // plain mapping (R3-style, passes post-timing)
    int n0 = (blockIdx.x & 63) << 6;

    // load x tile (coalesced along n)
    const float* xb = x + (size_t)b * CC * NN;
    #pragma unroll
    for (int it = 0; it < 16; ++it) {
        int idx = it * 256 + t, c = idx >> 6, nn = idx & 63;
        xt[c][nn] = xb[c * NN + n0 + nn];
    }
    // build Wcmb B-fragments: Wcmb[k][o2] = (o2<64 ? Wa-Wb : Wb)[k][o2&63]
    {
        __hip_bfloat16* wlu = (__hip_bfloat16*)wfl;
        int o = t & 63, h = t >> 6;
        #pragma unroll
        for (int kk = 0; kk < 16; ++kk) {
            int k = h * 16 + kk;
            float wa = W[k * OO + o];          // coalesced (o consecutive)
            float wb = W[(64 + k) * OO + o];
            int g = (k >> 3) & 3, j = k & 7, ks = k >> 5;
            int lane = (g << 4) | (o & 15);
            int fsA = ks * 8 + (o >> 4);       // o2 = o      (F part)
            int fsB = fsA + 4;                 // o2 = 64 + o (G part)
            wlu[((fsA * 64 + lane) << 3) | j] = __float2bfloat16(wa - wb);
            wlu[((fsB * 64 + lane) << 3) | j] = __float2bfloat16(wb);
        }
    }
    __syncthreads();

    Frag wf[2][8];
    #pragma unroll
    for (int ks = 0; ks < 2; ++ks)
        #pragma unroll
        for (int ot = 0; ot < 8; ++ot)
            wf[ks][ot].i = wfl[ks * 8 + ot][l];

    f32x4 acc[8];
    #pragma unroll
    for (int ot = 0; ot < 8; ++ot) {
        float bv = (ot < 4) ? bias[ot * 16 + (l & 15)] : 0.0f;
        acc[ot] = f32x4{bv, bv, bv, bv};
    }

    int node = (w << 4) + (l & 15);   // A row = lane&15
    #pragma unroll
    for (int ks = 0; ks < 2; ++ks) {
        PackA a;
        #pragma unroll
        for (int j = 0; j < 8; ++j)
            a.h[j] = __float2bfloat16(xt[ks * 32 + ((l >> 4) << 3) + j][node]);
        #pragma unroll
        for (int ot = 0; ot < 8; ++ot)
            acc[ot] = __builtin_amdgcn_mfma_f32_16x16x32_bf16(a.v, wf[ks][ot].v, acc[ot], 0, 0, 0);
    }

    // D: col = lane&15, row = (lane>>4)*4 + r  (m89-verified layout)
    size_t base = ((size_t)b * NN + n0 + (w << 4)) * 128;
    #pragma unroll
    for (int ot = 0; ot < 8; ++ot)
        #pragma unroll
        for (int r = 0; r < 4; ++r) {
            int nd = ((l >> 4) << 2) + r;
            FG[base + (size_t)nd * 128 + ot * 16 + (l & 15)] = __float2bfloat16(acc[ot][r]);
        }
    __threadfence();   // device-scope release: FG visible to all XCDs
}

// ---------------- k2: out[b][o][n] = relu(F[n][o] + max_k G[src[n][k]][o]) ----------------
// Wave handles 8 nodes; lane = o. Each gather: 64 lanes x 2B = 128B contiguous.
__global__ __launch_bounds__(256, 4) void gather_max(
    const int* __restrict__ ei, const unsigned short* __restrict__ FG,
    float* __restrict__ out) {
    __shared__ float otile[64][33];   // [o][node_local], 33-stride -> conflict-free
    __threadfence();                  // device-scope acquire before reading FG
    int t = threadIdx.x, w = t >> 6, l = t & 63;
    int b = blockIdx.x >> 7;          // plain mapping (R3-style)
    int n0 = (blockIdx.x & 127) << 5;

    const int* srcp = ei + (size_t)b * NN * KK;   // ei[0][b]
    size_t bbase = (size_t)b * NN;
    int nb = n0 + (w << 3);

    int idxv[8]; unsigned short fv[8];
    #pragma unroll
    for (int i = 0; i < 8; ++i) idxv[i] = srcp[(nb + i) * KK + (l & 15)];
    #pragma unroll
    for (int i = 0; i < 8; ++i) fv[i] = FG[(bbase + nb + i) * 128 + l];

    #pragma unroll
    for (int i = 0; i < 8; ++i) {
        float m = -3.4e38f;
        #pragma unroll
        for (int k = 0; k < 16; ++k) {
            int vk = __shfl(idxv[i], k);                         // lane k holds src[n][k]
            m = fmaxf(m, bf2f(FG[(bbase + vk) * 128 + 64 + l])); // coalesced 128B
        }
        otile[l][(w << 3) + i] = fmaxf(bf2f(fv[i]) + m, 0.0f);   // relu
    }
    __syncthreads();

    float* ob = out + (size_t)b * OO * NN;
    #pragma unroll
    for (int it = 0; it < 8; ++it) {
        int idx = it * 256 + t, o = idx >> 5, nn = idx & 31;
        ob[(size_t)o * NN + n0 + nn] = otile[o][nn];            // coalesced 128B rows
    }
}

extern "C" void kernel_launch(void* const* d_in, const int* in_sizes, int n_in,
                              void* d_out, int out_size, void* d_ws, size_t ws_size,
                              hipStream_t stream) {
    const float* x    = (const float*)d_in[0];   // [B,C,N,1] f32
    const int*   ei   = (const int*)d_in[1];     // [2,B,N,K] i32
    const float* W    = (const float*)d_in[2];   // [128,64] f32
    const float* bias = (const float*)d_in[3];   // [64] f32
    float* out = (float*)d_out;                  // [B,O,N,1] f32

    __hip_bfloat16* FG = (__hip_bfloat16*)d_ws;  // [B*N][128] bf16 = 8 MB

    hipLaunchKernelGGL(fg_gemm, dim3(BB * (NN / 64)), dim3(256), 0, stream,
                       x, W, bias, FG);
    hipLaunchKernelGGL(gather_max, dim3(BB * (NN / 32)), dim3(256), 0, stream,
                       ei, (const unsigned short*)FG, out);
}

// Round 8
// 24.515 us; speedup vs baseline: 6.4253x; 6.4253x over previous
//
#include <hip/hip_runtime.h>
#include <hip/hip_bf16.h>

// EdgeConv: B=8, C=64, N=4096, K=16, O=64
// Key identity: out[n] = relu(F[n] + max_k G[src[n,k]]),
//   F = x@(Wa-Wb)+bias, G = x@Wb   (max commutes with lane-constant add; relu with max)
// k1: dense GEMM -> FG[B*N][128] bf16 (cols 0-63 = F, 64-127 = G)
// k2: per-node wave: 16 coalesced 128B G-row gathers + fmax + relu, coalesced out.
//
// Correctness config (empirical, 4 rounds of evidence):
//  - plain block mapping (R6's bid&7 XCD swizzle -> post-timing stale-G divergence)
//  - NO __threadfence(): same-stream dispatch ordering already provides
//    release/acquire between dependent kernels. R7's entry-fence lowered to an
//    L2 invalidate per block -> L2 thrash during the gather phase (82us, 96cy/gather).

#define BB 8
#define CC 64
#define NN 4096
#define KK 16
#define OO 64

typedef __bf16 bf16x8 __attribute__((ext_vector_type(8)));
typedef float f32x4 __attribute__((ext_vector_type(4)));

union Frag { int4 i; bf16x8 v; };
union PackA { bf16x8 v; __hip_bfloat16 h[8]; };

static __device__ __forceinline__ float bf2f(unsigned short u) {
    union { unsigned int i; float f; } c; c.i = ((unsigned int)u) << 16; return c.f;
}

// ---------------- k1: FG = [x@(Wa-Wb)+bias | x@Wb] ----------------
// Block: 64 nodes of one batch. M=64, N2=128, K=64. 4 waves, 16 MFMA each.
__global__ __launch_bounds__(256, 3) void fg_gemm(
    const float* __restrict__ x, const float* __restrict__ W,
    const float* __restrict__ bias, __hip_bfloat16* __restrict__ FG) {
    __shared__ float xt[64][65];      // [c][node] f32, +1 pad
    __shared__ int4 wfl[16][64];      // B-frags: [ks*8+ot][lane]

    int t = threadIdx.x, w = t >> 6, l = t & 63;
    int b = blockIdx.x >> 6;          // plain mapping
    int n0 = (blockIdx.x & 63) << 6;

    // load x tile (coalesced along n)
    const float* xb = x + (size_t)b * CC * NN;
    #pragma unroll
    for (int it = 0; it < 16; ++it) {
        int idx = it * 256 + t, c = idx >> 6, nn = idx & 63;
        xt[c][nn] = xb[c * NN + n0 + nn];
    }
    // build Wcmb B-fragments: Wcmb[k][o2] = (o2<64 ? Wa-Wb : Wb)[k][o2&63]
    {
        __hip_bfloat16* wlu = (__hip_bfloat16*)wfl;
        int o = t & 63, h = t >> 6;
        #pragma unroll
        for (int kk = 0; kk < 16; ++kk) {
            int k = h * 16 + kk;
            float wa = W[k * OO + o];          // coalesced (o consecutive)
            float wb = W[(64 + k) * OO + o];
            int g = (k >> 3) & 3, j = k & 7, ks = k >> 5;
            int lane = (g << 4) | (o & 15);
            int fsA = ks * 8 + (o >> 4);       // o2 = o      (F part)
            int fsB = fsA + 4;                 // o2 = 64 + o (G part)
            wlu[((fsA * 64 + lane) << 3) | j] = __float2bfloat16(wa - wb);
            wlu[((fsB * 64 + lane) << 3) | j] = __float2bfloat16(wb);
        }
    }
    __syncthreads();

    Frag wf[2][8];
    #pragma unroll
    for (int ks = 0; ks < 2; ++ks)
        #pragma unroll
        for (int ot = 0; ot < 8; ++ot)
            wf[ks][ot].i = wfl[ks * 8 + ot][l];

    f32x4 acc[8];
    #pragma unroll
    for (int ot = 0; ot < 8; ++ot) {
        float bv = (ot < 4) ? bias[ot * 16 + (l & 15)] : 0.0f;
        acc[ot] = f32x4{bv, bv, bv, bv};
    }

    int node = (w << 4) + (l & 15);   // A row = lane&15
    #pragma unroll
    for (int ks = 0; ks < 2; ++ks) {
        PackA a;
        #pragma unroll
        for (int j = 0; j < 8; ++j)
            a.h[j] = __float2bfloat16(xt[ks * 32 + ((l >> 4) << 3) + j][node]);
        #pragma unroll
        for (int ot = 0; ot < 8; ++ot)
            acc[ot] = __builtin_amdgcn_mfma_f32_16x16x32_bf16(a.v, wf[ks][ot].v, acc[ot], 0, 0, 0);
    }

    // D: col = lane&15, row = (lane>>4)*4 + r  (m89-verified layout)
    size_t base = ((size_t)b * NN + n0 + (w << 4)) * 128;
    #pragma unroll
    for (int ot = 0; ot < 8; ++ot)
        #pragma unroll
        for (int r = 0; r < 4; ++r) {
            int nd = ((l >> 4) << 2) + r;
            FG[base + (size_t)nd * 128 + ot * 16 + (l & 15)] = __float2bfloat16(acc[ot][r]);
        }
}

// ---------------- k2: out[b][o][n] = relu(F[n][o] + max_k G[src[n][k]][o]) ----------------
// Wave handles 8 nodes; lane = o. Each gather: 64 lanes x 2B = 128B contiguous.
__global__ __launch_bounds__(256, 4) void gather_max(
    const int* __restrict__ ei, const unsigned short* __restrict__ FG,
    float* __restrict__ out) {
    __shared__ float otile[64][33];   // [o][node_local], 33-stride -> conflict-free
    int t = threadIdx.x, w = t >> 6, l = t & 63;
    int b = blockIdx.x >> 7;          // plain mapping
    int n0 = (blockIdx.x & 127) << 5;

    const int* srcp = ei + (size_t)b * NN * KK;   // ei[0][b]
    size_t bbase = (size_t)b * NN;
    int nb = n0 + (w << 3);

    int idxv[8]; unsigned short fv[8];
    #pragma unroll
    for (int i = 0; i < 8; ++i) idxv[i] = srcp[(nb + i) * KK + (l & 15)];
    #pragma unroll
    for (int i = 0; i < 8; ++i) fv[i] = FG[(bbase + nb + i) * 128 + l];

    #pragma unroll
    for (int i = 0; i < 8; ++i) {
        float m = -3.4e38f;
        #pragma unroll
        for (int k = 0; k < 16; ++k) {
            int vk = __shfl(idxv[i], k);                         // lane k holds src[n][k]
            m = fmaxf(m, bf2f(FG[(bbase + vk) * 128 + 64 + l])); // coalesced 128B
        }
        otile[l][(w << 3) + i] = fmaxf(bf2f(fv[i]) + m, 0.0f);   // relu
    }
    __syncthreads();

    float* ob = out + (size_t)b * OO * NN;
    #pragma unroll
    for (int it = 0; it < 8; ++it) {
        int idx = it * 256 + t, o = idx >> 5, nn = idx & 31;
        ob[(size_t)o * NN + n0 + nn] = otile[o][nn];            // coalesced 128B rows
    }
}

extern "C" void kernel_launch(void* const* d_in, const int* in_sizes, int n_in,
                              void* d_out, int out_size, void* d_ws, size_t ws_size,
                              hipStream_t stream) {
    const float* x    = (const float*)d_in[0];   // [B,C,N,1] f32
    const int*   ei   = (const int*)d_in[1];     // [2,B,N,K] i32
    const float* W    = (const float*)d_in[2];   // [128,64] f32
    const float* bias = (const float*)d_in[3];   // [64] f32
    float* out = (float*)d_out;                  // [B,O,N,1] f32

    __hip_bfloat16* FG = (__hip_bfloat16*)d_ws;  // [B*N][128] bf16 = 8 MB

    hipLaunchKernelGGL(fg_gemm, dim3(BB * (NN / 64)), dim3(256), 0, stream,
                       x, W, bias, FG);
    hipLaunchKernelGGL(gather_max, dim3(BB * (NN / 32)), dim3(256), 0, stream,
                       ei, (const unsigned short*)FG, out);
}

// Round 9
// 24.016 us; speedup vs baseline: 6.5588x; 1.0208x over previous
//
#include <hip/hip_runtime.h>
#include <hip/hip_bf16.h>

// EdgeConv: B=8, C=64, N=4096, K=16, O=64
// Key identity: out[n] = relu(F[n] + max_k G[src[n,k]]),
//   F = x@(Wa-Wb)+bias, G = x@Wb   (max commutes with lane-constant add; relu with max)
// k1: dense GEMM -> FG[B*N][128] bf16 (cols 0-63 = F, 64-127 = G)
// k2: per-node wave, half-wave ushort2 gathers (one instr = two full G rows).
//
// Correctness config (empirical, 5 rounds):
//  - plain block mapping (R6's bid&7 XCD swizzle -> post-timing stale-G divergence)
//  - NO __threadfence(): same-stream dispatch ordering provides release/acquire;
//    R7's entry fence caused per-block L2 invalidates -> 82us gather (96cy/gather).

#define BB 8
#define CC 64
#define NN 4096
#define KK 16
#define OO 64

typedef __bf16 bf16x8 __attribute__((ext_vector_type(8)));
typedef float f32x4 __attribute__((ext_vector_type(4)));

union Frag { int4 i; bf16x8 v; };
union PackA { bf16x8 v; __hip_bfloat16 h[8]; };

// ---------------- k1: FG = [x@(Wa-Wb)+bias | x@Wb] ----------------
// Block: 64 nodes of one batch. M=64, N2=128, K=64. 4 waves, 16 MFMA each.
__global__ __launch_bounds__(256, 3) void fg_gemm(
    const float* __restrict__ x, const float* __restrict__ W,
    const float* __restrict__ bias, __hip_bfloat16* __restrict__ FG) {
    __shared__ float xt[64][65];      // [c][node] f32, +1 pad
    __shared__ int4 wfl[16][64];      // B-frags: [ks*8+ot][lane]

    int t = threadIdx.x, w = t >> 6, l = t & 63;
    int b = blockIdx.x >> 6;          // plain mapping
    int n0 = (blockIdx.x & 63) << 6;

    // load x tile (float4, coalesced along n)
    const float* xb = x + (size_t)b * CC * NN;
    #pragma unroll
    for (int it = 0; it < 4; ++it) {
        int idx = it * 256 + t;       // 1024 float4 = 64 rows x 16
        int c = idx >> 4, q = idx & 15;
        float4 v = *(const float4*)(xb + (size_t)c * NN + n0 + q * 4);
        xt[c][q * 4 + 0] = v.x; xt[c][q * 4 + 1] = v.y;
        xt[c][q * 4 + 2] = v.z; xt[c][q * 4 + 3] = v.w;
    }
    // build Wcmb B-fragments: Wcmb[k][o2] = (o2<64 ? Wa-Wb : Wb)[k][o2&63]
    {
        __hip_bfloat16* wlu = (__hip_bfloat16*)wfl;
        int o = t & 63, h = t >> 6;
        #pragma unroll
        for (int kk = 0; kk < 16; ++kk) {
            int k = h * 16 + kk;
            float wa = W[k * OO + o];          // coalesced (o consecutive)
            float wb = W[(64 + k) * OO + o];
            int g = (k >> 3) & 3, j = k & 7, ks = k >> 5;
            int lane = (g << 4) | (o & 15);
            int fsA = ks * 8 + (o >> 4);       // o2 = o      (F part)
            int fsB = fsA + 4;                 // o2 = 64 + o (G part)
            wlu[((fsA * 64 + lane) << 3) | j] = __float2bfloat16(wa - wb);
            wlu[((fsB * 64 + lane) << 3) | j] = __float2bfloat16(wb);
        }
    }
    __syncthreads();

    Frag wf[2][8];
    #pragma unroll
    for (int ks = 0; ks < 2; ++ks)
        #pragma unroll
        for (int ot = 0; ot < 8; ++ot)
            wf[ks][ot].i = wfl[ks * 8 + ot][l];

    f32x4 acc[8];
    #pragma unroll
    for (int ot = 0; ot < 8; ++ot) {
        float bv = (ot < 4) ? bias[ot * 16 + (l & 15)] : 0.0f;
        acc[ot] = f32x4{bv, bv, bv, bv};
    }

    int node = (w << 4) + (l & 15);   // A row = lane&15
    #pragma unroll
    for (int ks = 0; ks < 2; ++ks) {
        PackA a;
        #pragma unroll
        for (int j = 0; j < 8; ++j)
            a.h[j] = __float2bfloat16(xt[ks * 32 + ((l >> 4) << 3) + j][node]);
        #pragma unroll
        for (int ot = 0; ot < 8; ++ot)
            acc[ot] = __builtin_amdgcn_mfma_f32_16x16x32_bf16(a.v, wf[ks][ot].v, acc[ot], 0, 0, 0);
    }

    // D: col = lane&15, row = (lane>>4)*4 + r  (m89-verified layout)
    size_t base = ((size_t)b * NN + n0 + (w << 4)) * 128;
    #pragma unroll
    for (int ot = 0; ot < 8; ++ot)
        #pragma unroll
        for (int r = 0; r < 4; ++r) {
            int nd = ((l >> 4) << 2) + r;
            FG[base + (size_t)nd * 128 + ot * 16 + (l & 15)] = __float2bfloat16(acc[ot][r]);
        }
}

// ---------------- k2: out[b][o][n] = relu(F[n][o] + max_k G[src[n][k]][o]) ----------------
// Half-wave gather: lanes 0-31 = even edges, 32-63 = odd edges; each lane loads
// ushort2 (2 channels). One instr fetches TWO full 128B G rows. Parities combine
// via shfl_xor(32). bf16->f32 is free bit-masking on the packed uint.
__global__ __launch_bounds__(256, 4) void gather_max(
    const int* __restrict__ ei, const unsigned int* __restrict__ FG2,
    float* __restrict__ out) {
    __shared__ float otile[64][33];   // [o][node_local]
    int t = threadIdx.x, w = t >> 6, l = t & 63;
    int b = blockIdx.x >> 7;          // plain mapping
    int n0 = (blockIdx.x & 127) << 5;

    const int* srcp = ei + (size_t)b * NN * KK;   // ei[0][b]
    size_t bbase = (size_t)b * NN;
    int nb = n0 + (w << 3);
    int h = l >> 5;                   // edge parity handled by this half-wave
    int cp = l & 31;                  // channel-pair index (channels 2cp, 2cp+1)

    int idxv[8];
    #pragma unroll
    for (int i = 0; i < 8; ++i) idxv[i] = srcp[(nb + i) * KK + (l & 15)];

    unsigned int fv[8];               // F channels (2cp,2cp+1), rows = own nodes
    #pragma unroll
    for (int i = 0; i < 8; ++i) fv[i] = FG2[((bbase + nb + i) << 6) + cp];

    #pragma unroll
    for (int i = 0; i < 8; ++i) {
        unsigned int g[8];
        #pragma unroll
        for (int j = 0; j < 8; ++j) {
            int vk = __shfl(idxv[i], (j << 1) | h);   // edge 2j+h's src node
            g[j] = FG2[(((size_t)bbase + vk) << 6) + 32 + cp];
        }
        float m0 = -3.4e38f, m1 = -3.4e38f;
        #pragma unroll
        for (int j = 0; j < 8; ++j) {
            m0 = fmaxf(m0, __uint_as_float(g[j] << 16));          // low bf16
            m1 = fmaxf(m1, __uint_as_float(g[j] & 0xffff0000u));  // high bf16
        }
        m0 = fmaxf(m0, __shfl_xor(m0, 32));   // combine edge parities
        m1 = fmaxf(m1, __shfl_xor(m1, 32));
        if (!h) {
            int nl = (w << 3) + i;
            otile[2 * cp + 0][nl] = fmaxf(__uint_as_float(fv[i] << 16) + m0, 0.0f);
            otile[2 * cp + 1][nl] = fmaxf(__uint_as_float(fv[i] & 0xffff0000u) + m1, 0.0f);
        }
    }
    __syncthreads();

    float* ob = out + (size_t)b * OO * NN;
    #pragma unroll
    for (int it = 0; it < 8; ++it) {
        int idx = it * 256 + t, o = idx >> 5, nn = idx & 31;
        ob[(size_t)o * NN + n0 + nn] = otile[o][nn];            // coalesced 128B rows
    }
}

extern "C" void kernel_launch(void* const* d_in, const int* in_sizes, int n_in,
                              void* d_out, int out_size, void* d_ws, size_t ws_size,
                              hipStream_t stream) {
    const float* x    = (const float*)d_in[0];   // [B,C,N,1] f32
    const int*   ei   = (const int*)d_in[1];     // [2,B,N,K] i32
    const float* W    = (const float*)d_in[2];   // [128,64] f32
    const float* bias = (const float*)d_in[3];   // [64] f32
    float* out = (float*)d_out;                  // [B,O,N,1] f32

    __hip_bfloat16* FG = (__hip_bfloat16*)d_ws;  // [B*N][128] bf16 = 8 MB

    hipLaunchKernelGGL(fg_gemm, dim3(BB * (NN / 64)), dim3(256), 0, stream,
                       x, W, bias, FG);
    hipLaunchKernelGGL(gather_max, dim3(BB * (NN / 32)), dim3(256), 0, stream,
                       ei, (const unsigned int*)FG, out);
}